// Round 3
// baseline (161.506 us; speedup 1.0000x reference)
//
#include <hip/hip_runtime.h>
#include <hip/hip_cooperative_groups.h>
namespace cg = cooperative_groups;

#define BB   2
#define TT   2048
#define DIN  128
#define NS   64
#define CL   32
#define NC   64      // TT/CL
#define NSUP 8
#define SUPW 8       // NC/NSUP
#define L2E  1.4426950408889634f

#if __has_builtin(__builtin_amdgcn_exp2f)
__device__ __forceinline__ float fexp2(float x) { return __builtin_amdgcn_exp2f(x); }
#else
__device__ __forceinline__ float fexp2(float x) { return exp2f(x); }
#endif

// ---- K1: xp = x @ W^T ; split into xcin / delta(sigmoid) / B / C ; a2 ----
__global__ __launch_bounds__(128) void k_proj(
    const float* __restrict__ x, const float* __restrict__ W,
    const float* __restrict__ A,
    float* __restrict__ xcin, float* __restrict__ delta,
    float* __restrict__ Bb, float* __restrict__ Cb, float* __restrict__ a2g) {
  __shared__ float xs[128 * 65];
  int tile = blockIdx.x, rg = blockIdx.y, tid = threadIdx.x;
  int base = tile * 128;
  const float4* __restrict__ x4 = (const float4*)(x + (size_t)base * 64);
  for (int i = tid; i < 128 * 16; i += 128) {
    float4 v = x4[i];
    int row = i >> 4, c4 = (i & 15) << 2;
    xs[row * 65 + c4 + 0] = v.x;
    xs[row * 65 + c4 + 1] = v.y;
    xs[row * 65 + c4 + 2] = v.z;
    xs[row * 65 + c4 + 3] = v.w;
  }
  if (tile == 0 && rg == 0 && tid < NS) {
    float s = 0.f;
    for (int m = 0; m < NS; ++m) s += A[tid * NS + m];
    a2g[tid] = s * L2E;
  }
  __syncthreads();
  float xr[64];
#pragma unroll
  for (int k = 0; k < 64; ++k) xr[k] = xs[tid * 65 + k];
  int bt = base + tid;
  for (int rr = 0; rr < 16; ++rr) {
    int r = rg * 16 + rr;
    const float* __restrict__ wrow = W + r * 64;
    float a0 = 0.f, a1 = 0.f, a2 = 0.f, a3 = 0.f;
#pragma unroll
    for (int k = 0; k < 64; k += 4) {
      a0 = fmaf(xr[k + 0], wrow[k + 0], a0);
      a1 = fmaf(xr[k + 1], wrow[k + 1], a1);
      a2 = fmaf(xr[k + 2], wrow[k + 2], a2);
      a3 = fmaf(xr[k + 3], wrow[k + 3], a3);
    }
    float acc = (a0 + a1) + (a2 + a3);
    if (r < 128) {
      xcin[(size_t)bt * DIN + r] = acc;
    } else if (r < 256) {
      delta[(size_t)bt * DIN + (r - 128)] = 1.f / (1.f + fexp2(-acc * L2E));
    } else if (r < 320) {
      Bb[(size_t)bt * NS + (r - 256)] = acc;
    } else {
      Cb[(size_t)bt * NS + (r - 320)] = acc;
    }
  }
}

// ---- K2: cooperative single kernel: P1 scan -> P2A/P2B combine -> P3 scan+y ----
__global__ __launch_bounds__(512) void k_main(
    const float* __restrict__ xcin, const float* __restrict__ delta,
    const float* __restrict__ Bb, const float* __restrict__ Cb,
    const float* __restrict__ a2g, const float* __restrict__ cw,
    const float* __restrict__ cb, const float* __restrict__ Dp,
    float* __restrict__ sumd, float* __restrict__ sumdS,
    float* __restrict__ hend, float* __restrict__ hinL,
    float* __restrict__ S, float* __restrict__ Csup,
    float* __restrict__ out) {
  __shared__ float xcs[(CL + 3) * DIN];  // 17.92 KB
  __shared__ float des[CL * DIN];        // 16 KB
  __shared__ float Bs[CL * NS];          // 8 KB
  __shared__ float Cs[CL * NS];          // 8 KB
  __shared__ float yred[16 * DIN];       // 8 KB

  cg::grid_group grid = cg::this_grid();
  const int bid = blockIdx.x, tid = threadIdx.x;
  const int c = bid >> 2, b = (bid >> 1) & 1, X = bid & 1;
  const int d = tid & 127, g = tid >> 7;
  const int t0 = c * CL;

  // zero out (exactly 1 float4 per thread covers all of out)
  ((float4*)out)[bid * 512 + tid] = make_float4(0.f, 0.f, 0.f, 0.f);

  // ---- stage chunk (c,b) into LDS ----
  {
    const float* __restrict__ xcB = xcin + (size_t)b * TT * DIN;
    for (int i = tid; i < (CL + 3) * 32; i += 512) {
      int row = i >> 5, c4 = i & 31;
      int t = t0 - 3 + row;
      float4 v = make_float4(0.f, 0.f, 0.f, 0.f);
      if (t >= 0) v = ((const float4*)(xcB + (size_t)t * DIN))[c4];
      ((float4*)xcs)[row * 32 + c4] = v;
    }
    for (int i = tid; i < CL * 32; i += 512) {
      int row = i >> 5, c4 = i & 31;
      ((float4*)des)[i] = ((const float4*)(delta + (size_t)(b * TT + t0 + row) * DIN))[c4];
    }
    for (int i = tid; i < CL * 16; i += 512) {
      int row = i >> 4, c4 = i & 15;
      ((float4*)Bs)[i] = ((const float4*)(Bb + (size_t)(b * TT + t0 + row) * NS))[c4];
      ((float4*)Cs)[i] = ((const float4*)(Cb + (size_t)(b * TT + t0 + row) * NS))[c4];
    }
  }
  float cw0 = cw[d * 4 + 0], cw1 = cw[d * 4 + 1], cw2 = cw[d * 4 + 2], cw3 = cw[d * 4 + 3];
  float cbd = cb[d], Dd = Dp[d];
  __syncthreads();

  // ---- P1: merged-direction local chunk scan (8 n per thread) ----
  {
    const int nb = X * 32 + g * 8;
    float a2r[8];
#pragma unroll
    for (int j = 0; j < 8; ++j) a2r[j] = a2g[nb + j];
    float hf[8], hr[8], Pp[8];
#pragma unroll
    for (int j = 0; j < 8; ++j) { hf[j] = 0.f; hr[j] = 0.f; Pp[j] = 1.f; }
    float sd = 0.f;
    float w0 = xcs[0 * DIN + d], w1 = xcs[1 * DIN + d], w2 = xcs[2 * DIN + d];
    for (int i = 0; i < CL; ++i) {
      float w3 = xcs[(i + 3) * DIN + d];
      float xconv = fmaf(cw0, w0, fmaf(cw1, w1, fmaf(cw2, w2, fmaf(cw3, w3, cbd))));
      float de = des[i * DIN + d];
      sd += de;
      float dxv = de * xconv;
#pragma unroll
      for (int jq = 0; jq < 2; ++jq) {
        float4 bq = *(const float4*)&Bs[i * NS + nb + jq * 4];
        float b0 = dxv * bq.x, b1 = dxv * bq.y, b2 = dxv * bq.z, b3 = dxv * bq.w;
        float e0 = fexp2(de * a2r[jq * 4 + 0]);
        float e1 = fexp2(de * a2r[jq * 4 + 1]);
        float e2 = fexp2(de * a2r[jq * 4 + 2]);
        float e3 = fexp2(de * a2r[jq * 4 + 3]);
        hf[jq * 4 + 0] = fmaf(e0, hf[jq * 4 + 0], b0);
        hr[jq * 4 + 0] = fmaf(Pp[jq * 4 + 0], b0, hr[jq * 4 + 0]);
        Pp[jq * 4 + 0] *= e0;
        hf[jq * 4 + 1] = fmaf(e1, hf[jq * 4 + 1], b1);
        hr[jq * 4 + 1] = fmaf(Pp[jq * 4 + 1], b1, hr[jq * 4 + 1]);
        Pp[jq * 4 + 1] *= e1;
        hf[jq * 4 + 2] = fmaf(e2, hf[jq * 4 + 2], b2);
        hr[jq * 4 + 2] = fmaf(Pp[jq * 4 + 2], b2, hr[jq * 4 + 2]);
        Pp[jq * 4 + 2] *= e2;
        hf[jq * 4 + 3] = fmaf(e3, hf[jq * 4 + 3], b3);
        hr[jq * 4 + 3] = fmaf(Pp[jq * 4 + 3], b3, hr[jq * 4 + 3]);
        Pp[jq * 4 + 3] *= e3;
      }
      w0 = w1; w1 = w2; w2 = w3;
    }
    size_t h0 = (((size_t)(0 * NC + c) * BB + b) * NS + nb) * DIN + d;
    size_t h1 = (((size_t)(1 * NC + c) * BB + b) * NS + nb) * DIN + d;
#pragma unroll
    for (int j = 0; j < 8; ++j) {
      hend[h0 + (size_t)j * DIN] = hf[j];
      hend[h1 + (size_t)j * DIN] = hr[j];
    }
    if (X == 0 && g == 0) sumd[(c * BB + b) * DIN + d] = sd;
  }
  grid.sync();

  // ---- P2A: within-super prefix (chains of 8), all blocks active ----
  for (int rep = 0; rep < 2; ++rep) {
    int idx = rep * (256 * 512) + bid * 512 + tid;  // 2*2*8*64*128 = 262144 tasks
    int dd = idx & 127;
    int n = (idx >> 7) & 63;
    int sp = (idx >> 13) & 7;
    int bd = idx >> 16;
    int b2 = bd >> 1, dir = bd & 1;
    float a2n = a2g[n];
    float carry = 0.f;
#pragma unroll
    for (int k = 0; k < SUPW; ++k) {
      int cc = sp * SUPW + (dir ? (SUPW - 1 - k) : k);
      float e = fexp2(a2n * sumd[(cc * BB + b2) * DIN + dd]);
      size_t hb = (((size_t)(dir * NC + cc) * BB + b2) * NS + n) * DIN + dd;
      float tmp = hend[hb];
      hinL[hb] = carry;
      carry = fmaf(e, carry, tmp);
    }
    S[((((size_t)dir * NSUP + sp) * BB + b2) * NS + n) * DIN + dd] = carry;
    if (n == 0 && dir == 0) {
      float ssum = 0.f;
#pragma unroll
      for (int k = 0; k < SUPW; ++k) ssum += sumd[((sp * SUPW + k) * BB + b2) * DIN + dd];
      sumdS[(sp * BB + b2) * DIN + dd] = ssum;
    }
  }
  grid.sync();

  // ---- P2B: chain over 8 supers (64 blocks active, loads hoisted) ----
  if (bid < 64) {
    int idx = bid * 512 + tid;  // 2*2*64*128 = 32768
    int dd = idx & 127;
    int n = (idx >> 7) & 63;
    int bd = idx >> 13;
    int b2 = bd >> 1, dir = bd & 1;
    float a2n = a2g[n];
    float carry = 0.f;
#pragma unroll
    for (int k = 0; k < NSUP; ++k) {
      int sp = dir ? (NSUP - 1 - k) : k;
      size_t sb = ((((size_t)dir * NSUP + sp) * BB + b2) * NS + n) * DIN + dd;
      Csup[sb] = carry;
      float e = fexp2(a2n * sumdS[(sp * BB + b2) * DIN + dd]);
      carry = fmaf(e, carry, S[sb]);
    }
  }
  grid.sync();

  // ---- P3: full local scan with reconstructed init; y; interleaved reduce ----
  {
    const int dir = X;
    const int nb3 = g * 16;
    float a2r16[16], h[16];
#pragma unroll
    for (int j = 0; j < 16; ++j) a2r16[j] = a2g[nb3 + j];
    int sp = c >> 3;
    float Sloc = 0.f;
    if (dir == 0) {
      for (int cc = sp * 8; cc < c; ++cc) Sloc += sumd[(cc * BB + b) * DIN + d];
    } else {
      for (int cc = c + 1; cc < sp * 8 + 8; ++cc) Sloc += sumd[(cc * BB + b) * DIN + d];
    }
    size_t hb0 = (((size_t)(dir * NC + c) * BB + b) * NS + nb3) * DIN + d;
    size_t sb0 = ((((size_t)dir * NSUP + sp) * BB + b) * NS + nb3) * DIN + d;
#pragma unroll
    for (int j = 0; j < 16; ++j) {
      float pe = fexp2(a2r16[j] * Sloc);
      h[j] = fmaf(pe, Csup[sb0 + (size_t)j * DIN], hinL[hb0 + (size_t)j * DIN]);
    }
    for (int r = 0; r < 8; ++r) {
      float yp0 = 0.f, yp1 = 0.f, yp2 = 0.f, yp3 = 0.f;
#pragma unroll
      for (int ii = 0; ii < 4; ++ii) {
        int k = r * 4 + ii;
        int i = dir ? (31 - k) : k;
        float x0 = xcs[i * DIN + d], x1 = xcs[(i + 1) * DIN + d];
        float x2 = xcs[(i + 2) * DIN + d], x3 = xcs[(i + 3) * DIN + d];
        float xconv = fmaf(cw0, x0, fmaf(cw1, x1, fmaf(cw2, x2, fmaf(cw3, x3, cbd))));
        float de = des[i * DIN + d];
        float dxv = de * xconv;
        float yv = (dir == 0 && g == 0) ? Dd * xconv : 0.f;
#pragma unroll
        for (int jq = 0; jq < 4; ++jq) {
          float4 bq = *(const float4*)&Bs[i * NS + nb3 + jq * 4];
          float4 cq = *(const float4*)&Cs[i * NS + nb3 + jq * 4];
          float e0 = fexp2(de * a2r16[jq * 4 + 0]);
          h[jq * 4 + 0] = fmaf(e0, h[jq * 4 + 0], dxv * bq.x);
          yv = fmaf(h[jq * 4 + 0], cq.x, yv);
          float e1 = fexp2(de * a2r16[jq * 4 + 1]);
          h[jq * 4 + 1] = fmaf(e1, h[jq * 4 + 1], dxv * bq.y);
          yv = fmaf(h[jq * 4 + 1], cq.y, yv);
          float e2 = fexp2(de * a2r16[jq * 4 + 2]);
          h[jq * 4 + 2] = fmaf(e2, h[jq * 4 + 2], dxv * bq.z);
          yv = fmaf(h[jq * 4 + 2], cq.z, yv);
          float e3 = fexp2(de * a2r16[jq * 4 + 3]);
          h[jq * 4 + 3] = fmaf(e3, h[jq * 4 + 3], dxv * bq.w);
          yv = fmaf(h[jq * 4 + 3], cq.w, yv);
        }
        if (ii == 0) yp0 = yv; else if (ii == 1) yp1 = yv; else if (ii == 2) yp2 = yv; else yp3 = yv;
      }
      yred[(g * 4 + 0) * DIN + d] = yp0;
      yred[(g * 4 + 1) * DIN + d] = yp1;
      yred[(g * 4 + 2) * DIN + d] = yp2;
      yred[(g * 4 + 3) * DIN + d] = yp3;
      __syncthreads();
      {
        int tt = tid >> 7, d2 = tid & 127;
        float s = (yred[(0 + tt) * DIN + d2] + yred[(4 + tt) * DIN + d2]) +
                  (yred[(8 + tt) * DIN + d2] + yred[(12 + tt) * DIN + d2]);
        int k2 = r * 4 + tt;
        int tg = t0 + (dir ? (31 - k2) : k2);
        unsafeAtomicAdd(&out[((size_t)b * TT + tg) * DIN + d2], s);
      }
      __syncthreads();
    }
  }
}

extern "C" void kernel_launch(void* const* d_in, const int* in_sizes, int n_in,
                              void* d_out, int out_size, void* d_ws, size_t ws_size,
                              hipStream_t stream) {
  const float* x  = (const float*)d_in[0];
  const float* W  = (const float*)d_in[1];
  const float* cw = (const float*)d_in[2];
  const float* cb = (const float*)d_in[3];
  const float* A  = (const float*)d_in[4];
  const float* Dp = (const float*)d_in[5];
  float* out = (float*)d_out;

  float* ws = (float*)d_ws;
  float* xcin  = ws;                       // 524288
  float* delta = xcin + 524288;            // 524288
  float* Bbuf  = delta + 524288;           // 262144
  float* Cbuf  = Bbuf + 262144;            // 262144
  float* a2g   = Cbuf + 262144;            // 128
  float* sumdb = a2g + 128;                // 16384
  float* sumdS = sumdb + 16384;            // 2048
  float* hendb = sumdS + 2048;             // 2097152
  float* hinL  = hendb + 2097152;          // 2097152
  float* Sb    = hinL + 2097152;           // 262144
  float* Csup  = Sb + 262144;              // 262144
  // total ~25.3 MB

  hipLaunchKernelGGL(k_proj, dim3(32, 24), dim3(128), 0, stream,
                     x, W, A, xcin, delta, Bbuf, Cbuf, a2g);

  void* kargs[] = {
    (void*)&xcin, (void*)&delta, (void*)&Bbuf, (void*)&Cbuf, (void*)&a2g,
    (void*)&cw, (void*)&cb, (void*)&Dp,
    (void*)&sumdb, (void*)&sumdS, (void*)&hendb, (void*)&hinL,
    (void*)&Sb, (void*)&Csup, (void*)&out
  };
  hipLaunchCooperativeKernel((void*)k_main, dim3(256), dim3(512), kargs, 0, stream);
}

// Round 4
// 81.043 us; speedup vs baseline: 1.9928x; 1.9928x over previous
//
#include <hip/hip_runtime.h>

#define BB   2
#define TT   2048
#define DIN  128
#define NS   64
#define CL   16
#define NC   128     // TT/CL
#define NSUP 16
#define SUPW 8       // NC/NSUP
#define L2E  1.4426950408889634f

#if __has_builtin(__builtin_amdgcn_exp2f)
__device__ __forceinline__ float fexp2(float x) { return __builtin_amdgcn_exp2f(x); }
#else
__device__ __forceinline__ float fexp2(float x) { return exp2f(x); }
#endif

// ---- K1: xp = x @ W^T ; split into xcin / delta(sigmoid) / B / C ; a2 ----
__global__ __launch_bounds__(128) void k_proj(
    const float* __restrict__ x, const float* __restrict__ W,
    const float* __restrict__ A,
    float* __restrict__ xcin, float* __restrict__ delta,
    float* __restrict__ Bb, float* __restrict__ Cb, float* __restrict__ a2g) {
  __shared__ float xs[128 * 65];
  int tile = blockIdx.x, rg = blockIdx.y, tid = threadIdx.x;
  int base = tile * 128;
  const float4* __restrict__ x4 = (const float4*)(x + (size_t)base * 64);
  for (int i = tid; i < 128 * 16; i += 128) {
    float4 v = x4[i];
    int row = i >> 4, c4 = (i & 15) << 2;
    xs[row * 65 + c4 + 0] = v.x;
    xs[row * 65 + c4 + 1] = v.y;
    xs[row * 65 + c4 + 2] = v.z;
    xs[row * 65 + c4 + 3] = v.w;
  }
  if (tile == 0 && rg == 0 && tid < NS) {
    float s = 0.f;
    for (int m = 0; m < NS; ++m) s += A[tid * NS + m];
    a2g[tid] = s * L2E;
  }
  __syncthreads();
  float xr[64];
#pragma unroll
  for (int k = 0; k < 64; ++k) xr[k] = xs[tid * 65 + k];
  int bt = base + tid;
  for (int rr = 0; rr < 16; ++rr) {
    int r = rg * 16 + rr;
    const float* __restrict__ wrow = W + r * 64;
    float a0 = 0.f, a1 = 0.f, a2 = 0.f, a3 = 0.f;
#pragma unroll
    for (int k = 0; k < 64; k += 4) {
      a0 = fmaf(xr[k + 0], wrow[k + 0], a0);
      a1 = fmaf(xr[k + 1], wrow[k + 1], a1);
      a2 = fmaf(xr[k + 2], wrow[k + 2], a2);
      a3 = fmaf(xr[k + 3], wrow[k + 3], a3);
    }
    float acc = (a0 + a1) + (a2 + a3);
    if (r < 128) {
      xcin[(size_t)bt * DIN + r] = acc;
    } else if (r < 256) {
      delta[(size_t)bt * DIN + (r - 128)] = 1.f / (1.f + fexp2(-acc * L2E));
    } else if (r < 320) {
      Bb[(size_t)bt * NS + (r - 256)] = acc;
    } else {
      Cb[(size_t)bt * NS + (r - 320)] = acc;
    }
  }
}

// ---- K2: merged fwd+rev local chunk scans (shared exp), LDS-staged ----
__global__ __launch_bounds__(1024) void k_scan1(
    const float* __restrict__ xcin, const float* __restrict__ delta,
    const float* __restrict__ Bb, const float* __restrict__ a2g,
    const float* __restrict__ cw, const float* __restrict__ cb,
    float* __restrict__ hend, float* __restrict__ sumd) {
  __shared__ float xcs[(CL + 3) * DIN];  // 9.7 KB
  __shared__ float des[CL * DIN];        // 8 KB
  __shared__ float Bs[CL * NS];          // 4 KB
  int c = blockIdx.x, b = blockIdx.y;
  int tid = threadIdx.x;
  int d = tid & 127, g = tid >> 7;       // 8 n-groups of 8
  int t0 = c * CL;
  {
    const float* __restrict__ xcB = xcin + (size_t)b * TT * DIN;
    for (int i = tid; i < (CL + 3) * 32; i += 1024) {
      int row = i >> 5, c4 = i & 31;
      int t = t0 - 3 + row;
      float4 v = make_float4(0.f, 0.f, 0.f, 0.f);
      if (t >= 0) v = ((const float4*)(xcB + (size_t)t * DIN))[c4];
      ((float4*)xcs)[i] = v;
    }
    for (int i = tid; i < CL * 32; i += 1024)
      ((float4*)des)[i] = ((const float4*)(delta + (size_t)(b * TT + t0) * DIN))[i];
    for (int i = tid; i < CL * 16; i += 1024)
      ((float4*)Bs)[i] = ((const float4*)(Bb + (size_t)(b * TT + t0) * NS))[i];
  }
  float cw0 = cw[d * 4 + 0], cw1 = cw[d * 4 + 1], cw2 = cw[d * 4 + 2], cw3 = cw[d * 4 + 3];
  float cbd = cb[d];
  int nb = g * 8;
  float a2r[8];
#pragma unroll
  for (int j = 0; j < 8; ++j) a2r[j] = a2g[nb + j];
  __syncthreads();
  float hf[8], hr[8], Pp[8];
#pragma unroll
  for (int j = 0; j < 8; ++j) { hf[j] = 0.f; hr[j] = 0.f; Pp[j] = 1.f; }
  float sd = 0.f;
  float w0 = xcs[0 * DIN + d], w1 = xcs[1 * DIN + d], w2 = xcs[2 * DIN + d];
  for (int i = 0; i < CL; ++i) {
    float w3 = xcs[(i + 3) * DIN + d];
    float xconv = fmaf(cw0, w0, fmaf(cw1, w1, fmaf(cw2, w2, fmaf(cw3, w3, cbd))));
    float de = des[i * DIN + d];
    sd += de;
    float dxv = de * xconv;
#pragma unroll
    for (int jq = 0; jq < 2; ++jq) {
      float4 bq = *(const float4*)&Bs[i * NS + nb + jq * 4];
      float b0 = dxv * bq.x, b1 = dxv * bq.y, b2 = dxv * bq.z, b3 = dxv * bq.w;
      float e0 = fexp2(de * a2r[jq * 4 + 0]);
      float e1 = fexp2(de * a2r[jq * 4 + 1]);
      float e2 = fexp2(de * a2r[jq * 4 + 2]);
      float e3 = fexp2(de * a2r[jq * 4 + 3]);
      hf[jq * 4 + 0] = fmaf(e0, hf[jq * 4 + 0], b0);
      hr[jq * 4 + 0] = fmaf(Pp[jq * 4 + 0], b0, hr[jq * 4 + 0]); Pp[jq * 4 + 0] *= e0;
      hf[jq * 4 + 1] = fmaf(e1, hf[jq * 4 + 1], b1);
      hr[jq * 4 + 1] = fmaf(Pp[jq * 4 + 1], b1, hr[jq * 4 + 1]); Pp[jq * 4 + 1] *= e1;
      hf[jq * 4 + 2] = fmaf(e2, hf[jq * 4 + 2], b2);
      hr[jq * 4 + 2] = fmaf(Pp[jq * 4 + 2], b2, hr[jq * 4 + 2]); Pp[jq * 4 + 2] *= e2;
      hf[jq * 4 + 3] = fmaf(e3, hf[jq * 4 + 3], b3);
      hr[jq * 4 + 3] = fmaf(Pp[jq * 4 + 3], b3, hr[jq * 4 + 3]); Pp[jq * 4 + 3] *= e3;
    }
    w0 = w1; w1 = w2; w2 = w3;
  }
  size_t h0 = (((size_t)(0 * NC + c) * BB + b) * NS + nb) * DIN + d;
  size_t h1 = (((size_t)(1 * NC + c) * BB + b) * NS + nb) * DIN + d;
#pragma unroll
  for (int j = 0; j < 8; ++j) {
    hend[h0 + (size_t)j * DIN] = hf[j];
    hend[h1 + (size_t)j * DIN] = hr[j];
  }
  if (g == 0) sumd[(c * BB + b) * DIN + d] = sd;
}

// ---- K3: within-super prefixes (8-chains, fully parallel) + delta prefixes ----
__global__ __launch_bounds__(512) void k_comb2A(
    const float* __restrict__ hend, float* __restrict__ hinL,
    const float* __restrict__ sumd, const float* __restrict__ a2g,
    float* __restrict__ S, float* __restrict__ sumdS,
    float* __restrict__ sumdPf, float* __restrict__ sumdPr) {
  int idx = blockIdx.x * 512 + threadIdx.x;   // 2*2*16*64*128 = 524288
  int dd = idx & 127;
  int n = (idx >> 7) & 63;
  int sp = (idx >> 13) & 15;
  int bd = idx >> 17;
  int b = bd >> 1, dir = bd & 1;
  float a2n = a2g[n];
  float carry = 0.f;
  float running = 0.f;
#pragma unroll
  for (int k = 0; k < SUPW; ++k) {
    int cc = sp * SUPW + (dir ? (SUPW - 1 - k) : k);
    float sdv = sumd[(cc * BB + b) * DIN + dd];
    if (n == 0) {
      if (dir) sumdPr[(cc * BB + b) * DIN + dd] = running;
      else     sumdPf[(cc * BB + b) * DIN + dd] = running;
      running += sdv;
      if (dir == 0 && k == SUPW - 1) sumdS[(sp * BB + b) * DIN + dd] = running;
    }
    float e = fexp2(a2n * sdv);
    size_t hb = (((size_t)(dir * NC + cc) * BB + b) * NS + n) * DIN + dd;
    float tmp = hend[hb];
    hinL[hb] = carry;
    carry = fmaf(e, carry, tmp);
  }
  S[((((size_t)dir * NSUP + sp) * BB + b) * NS + n) * DIN + dd] = carry;
}

// ---- K4: chain over 16 supers (loads hoisted) -> Csup ----
__global__ __launch_bounds__(256) void k_comb2B(
    const float* __restrict__ S, const float* __restrict__ sumdS,
    const float* __restrict__ a2g, float* __restrict__ Csup) {
  int idx = blockIdx.x * 256 + threadIdx.x;   // 2*2*64*128 = 32768
  int dd = idx & 127;
  int n = (idx >> 7) & 63;
  int bd = idx >> 13;
  int b = bd >> 1, dir = bd & 1;
  float a2n = a2g[n];
  float sdS[NSUP], Sv[NSUP];
#pragma unroll
  for (int sp = 0; sp < NSUP; ++sp) {
    sdS[sp] = sumdS[(sp * BB + b) * DIN + dd];
    Sv[sp] = S[((((size_t)dir * NSUP + sp) * BB + b) * NS + n) * DIN + dd];
  }
  float carry = 0.f;
#pragma unroll
  for (int k = 0; k < NSUP; ++k) {
    int sp = dir ? (NSUP - 1 - k) : k;
    Csup[((((size_t)dir * NSUP + sp) * BB + b) * NS + n) * DIN + dd] = carry;
    carry = fmaf(fexp2(a2n * sdS[sp]), carry, Sv[sp]);
  }
}

// ---- K5: full local scans with reconstructed init; y reduce + atomic out ----
__global__ __launch_bounds__(512) void k_scan2(
    const float* __restrict__ xcin, const float* __restrict__ delta,
    const float* __restrict__ Bb, const float* __restrict__ Cb,
    const float* __restrict__ a2g, const float* __restrict__ cw,
    const float* __restrict__ cb, const float* __restrict__ Dp,
    const float* __restrict__ hinL, const float* __restrict__ Csup,
    const float* __restrict__ sumdPf, const float* __restrict__ sumdPr,
    float* __restrict__ out) {
  __shared__ float yred[4 * CL * DIN];   // 32 KB
  int c = blockIdx.x;
  int b = blockIdx.y >> 1, dir = blockIdx.y & 1;
  int tid = threadIdx.x;
  int d = tid & 127;
  int g = tid >> 7;
  float cw0 = cw[d * 4 + 0], cw1 = cw[d * 4 + 1], cw2 = cw[d * 4 + 2], cw3 = cw[d * 4 + 3];
  float cbd = cb[d];
  float Dd = Dp[d];
  int nb = g * 16;
  float a2r[16];
#pragma unroll
  for (int j = 0; j < 16; ++j) a2r[j] = a2g[nb + j];
  int sp = c >> 3;
  float Sloc = dir ? sumdPr[(c * BB + b) * DIN + d] : sumdPf[(c * BB + b) * DIN + d];
  float h[16];
  size_t hb0 = (((size_t)(dir * NC + c) * BB + b) * NS + nb) * DIN + d;
  size_t sb0 = ((((size_t)dir * NSUP + sp) * BB + b) * NS + nb) * DIN + d;
#pragma unroll
  for (int j = 0; j < 16; ++j) {
    float pe = fexp2(a2r[j] * Sloc);
    h[j] = fmaf(pe, Csup[sb0 + (size_t)j * DIN], hinL[hb0 + (size_t)j * DIN]);
  }
  int t0 = c * CL;
  const float* __restrict__ xcB = xcin + (size_t)b * TT * DIN + d;
  const float* __restrict__ deB = delta + (size_t)b * TT * DIN + d;
  const float* __restrict__ BbB = Bb + (size_t)b * TT * NS + nb;
  const float* __restrict__ CbB = Cb + (size_t)b * TT * NS + nb;
  float yp[CL];
  float w0, w1, w2, w3;
  bool addD = (g == 0) && (dir == 0);
  if (dir == 0) {
    int t = t0;
    w0 = (t - 3 >= 0) ? xcB[(t - 3) * DIN] : 0.f;
    w1 = (t - 2 >= 0) ? xcB[(t - 2) * DIN] : 0.f;
    w2 = (t - 1 >= 0) ? xcB[(t - 1) * DIN] : 0.f;
    w3 = xcB[t * DIN];
    for (int i = 0; i < CL; ++i) {
      float xconv = fmaf(cw0, w0, fmaf(cw1, w1, fmaf(cw2, w2, fmaf(cw3, w3, cbd))));
      float de = deB[t * DIN];
      float dxv = de * xconv;
      float yv = addD ? Dd * xconv : 0.f;
#pragma unroll
      for (int jq = 0; jq < 4; ++jq) {
        float4 bq = *(const float4*)&BbB[t * NS + jq * 4];
        float4 cq = *(const float4*)&CbB[t * NS + jq * 4];
        float e0 = fexp2(de * a2r[jq * 4 + 0]);
        h[jq * 4 + 0] = fmaf(e0, h[jq * 4 + 0], dxv * bq.x); yv = fmaf(h[jq * 4 + 0], cq.x, yv);
        float e1 = fexp2(de * a2r[jq * 4 + 1]);
        h[jq * 4 + 1] = fmaf(e1, h[jq * 4 + 1], dxv * bq.y); yv = fmaf(h[jq * 4 + 1], cq.y, yv);
        float e2 = fexp2(de * a2r[jq * 4 + 2]);
        h[jq * 4 + 2] = fmaf(e2, h[jq * 4 + 2], dxv * bq.z); yv = fmaf(h[jq * 4 + 2], cq.z, yv);
        float e3 = fexp2(de * a2r[jq * 4 + 3]);
        h[jq * 4 + 3] = fmaf(e3, h[jq * 4 + 3], dxv * bq.w); yv = fmaf(h[jq * 4 + 3], cq.w, yv);
      }
      yp[i] = yv;
      if (i < CL - 1) { ++t; w0 = w1; w1 = w2; w2 = w3; w3 = xcB[t * DIN]; }
    }
  } else {
    int t = t0 + CL - 1;
    w3 = xcB[t * DIN];
    w2 = xcB[(t - 1) * DIN];
    w1 = xcB[(t - 2) * DIN];
    w0 = xcB[(t - 3) * DIN];
    for (int i = 0; i < CL; ++i) {
      float xconv = fmaf(cw0, w0, fmaf(cw1, w1, fmaf(cw2, w2, fmaf(cw3, w3, cbd))));
      float de = deB[t * DIN];
      float dxv = de * xconv;
      float yv = 0.f;
#pragma unroll
      for (int jq = 0; jq < 4; ++jq) {
        float4 bq = *(const float4*)&BbB[t * NS + jq * 4];
        float4 cq = *(const float4*)&CbB[t * NS + jq * 4];
        float e0 = fexp2(de * a2r[jq * 4 + 0]);
        h[jq * 4 + 0] = fmaf(e0, h[jq * 4 + 0], dxv * bq.x); yv = fmaf(h[jq * 4 + 0], cq.x, yv);
        float e1 = fexp2(de * a2r[jq * 4 + 1]);
        h[jq * 4 + 1] = fmaf(e1, h[jq * 4 + 1], dxv * bq.y); yv = fmaf(h[jq * 4 + 1], cq.y, yv);
        float e2 = fexp2(de * a2r[jq * 4 + 2]);
        h[jq * 4 + 2] = fmaf(e2, h[jq * 4 + 2], dxv * bq.z); yv = fmaf(h[jq * 4 + 2], cq.z, yv);
        float e3 = fexp2(de * a2r[jq * 4 + 3]);
        h[jq * 4 + 3] = fmaf(e3, h[jq * 4 + 3], dxv * bq.w); yv = fmaf(h[jq * 4 + 3], cq.w, yv);
      }
      yp[i] = yv;
      if (i < CL - 1) { --t; w3 = w2; w2 = w1; w1 = w0; w0 = (t - 3 >= 0) ? xcB[(t - 3) * DIN] : 0.f; }
    }
  }
#pragma unroll
  for (int i = 0; i < CL; ++i) yred[(g * CL + i) * DIN + d] = yp[i];
  __syncthreads();
#pragma unroll
  for (int k = 0; k < 4; ++k) {
    int p = k * 512 + tid;
    int i = p >> 7, d2 = p & 127;
    float s = (yred[(0 * CL + i) * DIN + d2] + yred[(1 * CL + i) * DIN + d2]) +
              (yred[(2 * CL + i) * DIN + d2] + yred[(3 * CL + i) * DIN + d2]);
    int t = dir ? (t0 + CL - 1 - i) : (t0 + i);
    unsafeAtomicAdd(&out[((size_t)b * TT + t) * DIN + d2], s);
  }
}

extern "C" void kernel_launch(void* const* d_in, const int* in_sizes, int n_in,
                              void* d_out, int out_size, void* d_ws, size_t ws_size,
                              hipStream_t stream) {
  const float* x  = (const float*)d_in[0];
  const float* W  = (const float*)d_in[1];
  const float* cw = (const float*)d_in[2];
  const float* cb = (const float*)d_in[3];
  const float* A  = (const float*)d_in[4];
  const float* Dp = (const float*)d_in[5];
  float* out = (float*)d_out;

  float* ws = (float*)d_ws;
  float* xcin   = ws;                      // 524288
  float* delta  = xcin + 524288;           // 524288
  float* Bbuf   = delta + 524288;          // 262144
  float* Cbuf   = Bbuf + 262144;           // 262144
  float* a2g    = Cbuf + 262144;           // 128
  float* sumd   = a2g + 128;               // 32768
  float* sumdPf = sumd + 32768;            // 32768
  float* sumdPr = sumdPf + 32768;          // 32768
  float* sumdS  = sumdPr + 32768;          // 4096
  float* hendb  = sumdS + 4096;            // 4194304
  float* hinL   = hendb + 4194304;         // 4194304
  float* Sb     = hinL + 4194304;          // 524288
  float* Csup   = Sb + 524288;             // 524288
  // total ~44.5 MB

  hipMemsetAsync(d_out, 0, (size_t)(BB * TT * DIN) * sizeof(float), stream);
  hipLaunchKernelGGL(k_proj,   dim3(32, 24), dim3(128), 0, stream,
                     x, W, A, xcin, delta, Bbuf, Cbuf, a2g);
  hipLaunchKernelGGL(k_scan1,  dim3(NC, BB), dim3(1024), 0, stream,
                     xcin, delta, Bbuf, a2g, cw, cb, hendb, sumd);
  hipLaunchKernelGGL(k_comb2A, dim3(1024), dim3(512), 0, stream,
                     hendb, hinL, sumd, a2g, Sb, sumdS, sumdPf, sumdPr);
  hipLaunchKernelGGL(k_comb2B, dim3(128), dim3(256), 0, stream,
                     Sb, sumdS, a2g, Csup);
  hipLaunchKernelGGL(k_scan2,  dim3(NC, BB * 2), dim3(512), 0, stream,
                     xcin, delta, Bbuf, Cbuf, a2g, cw, cb, Dp, hinL, Csup,
                     sumdPf, sumdPr, out);
}

// Round 5
// 74.447 us; speedup vs baseline: 2.1694x; 1.0886x over previous
//
#include <hip/hip_runtime.h>

#define BB   2
#define TT   2048
#define DIN  128
#define NS   64
#define CL   16
#define NC   128     // TT/CL
#define NSUP 16
#define SUPW 8       // NC/NSUP
#define L2E  1.4426950408889634f

#if __has_builtin(__builtin_amdgcn_exp2f)
__device__ __forceinline__ float fexp2(float x) { return __builtin_amdgcn_exp2f(x); }
#else
__device__ __forceinline__ float fexp2(float x) { return exp2f(x); }
#endif

// ---- K1: xp = x @ W^T ; split into xcin / delta(sigmoid) / B / C ; a2 ----
__global__ __launch_bounds__(128) void k_proj(
    const float* __restrict__ x, const float* __restrict__ W,
    const float* __restrict__ A,
    float* __restrict__ xcin, float* __restrict__ delta,
    float* __restrict__ Bb, float* __restrict__ Cb, float* __restrict__ a2g) {
  __shared__ float xs[128 * 65];
  int tile = blockIdx.x, rg = blockIdx.y, tid = threadIdx.x;
  int base = tile * 128;
  const float4* __restrict__ x4 = (const float4*)(x + (size_t)base * 64);
  for (int i = tid; i < 128 * 16; i += 128) {
    float4 v = x4[i];
    int row = i >> 4, c4 = (i & 15) << 2;
    xs[row * 65 + c4 + 0] = v.x;
    xs[row * 65 + c4 + 1] = v.y;
    xs[row * 65 + c4 + 2] = v.z;
    xs[row * 65 + c4 + 3] = v.w;
  }
  if (tile == 0 && rg == 0 && tid < NS) {
    float s = 0.f;
    for (int m = 0; m < NS; ++m) s += A[tid * NS + m];
    a2g[tid] = s * L2E;
  }
  __syncthreads();
  float xr[64];
#pragma unroll
  for (int k = 0; k < 64; ++k) xr[k] = xs[tid * 65 + k];
  int bt = base + tid;
#pragma unroll 4
  for (int rr = 0; rr < 16; ++rr) {
    int r = rg * 16 + rr;
    const float* __restrict__ wrow = W + r * 64;
    float a0 = 0.f, a1 = 0.f, a2 = 0.f, a3 = 0.f;
#pragma unroll
    for (int k = 0; k < 64; k += 4) {
      a0 = fmaf(xr[k + 0], wrow[k + 0], a0);
      a1 = fmaf(xr[k + 1], wrow[k + 1], a1);
      a2 = fmaf(xr[k + 2], wrow[k + 2], a2);
      a3 = fmaf(xr[k + 3], wrow[k + 3], a3);
    }
    float acc = (a0 + a1) + (a2 + a3);
    if (r < 128) {
      xcin[(size_t)bt * DIN + r] = acc;
    } else if (r < 256) {
      delta[(size_t)bt * DIN + (r - 128)] = 1.f / (1.f + fexp2(-acc * L2E));
    } else if (r < 320) {
      Bb[(size_t)bt * NS + (r - 256)] = acc;
    } else {
      Cb[(size_t)bt * NS + (r - 320)] = acc;
    }
  }
}

// ---- K2: merged fwd+rev local chunk scans (shared exp), LDS-staged ----
__global__ __launch_bounds__(1024) void k_scan1(
    const float* __restrict__ xcin, const float* __restrict__ delta,
    const float* __restrict__ Bb, const float* __restrict__ a2g,
    const float* __restrict__ cw, const float* __restrict__ cb,
    float* __restrict__ hend, float* __restrict__ sumd) {
  __shared__ float xcs[(CL + 3) * DIN];  // 9.7 KB
  __shared__ float des[CL * DIN];        // 8 KB
  __shared__ float Bs[CL * NS];          // 4 KB
  int c = blockIdx.x, b = blockIdx.y;
  int tid = threadIdx.x;
  int d = tid & 127;
  int g = __builtin_amdgcn_readfirstlane(tid >> 7);  // 8 n-groups of 8
  int t0 = c * CL;
  {
    const float* __restrict__ xcB = xcin + (size_t)b * TT * DIN;
    for (int i = tid; i < (CL + 3) * 32; i += 1024) {
      int row = i >> 5, c4 = i & 31;
      int t = t0 - 3 + row;
      float4 v = make_float4(0.f, 0.f, 0.f, 0.f);
      if (t >= 0) v = ((const float4*)(xcB + (size_t)t * DIN))[c4];
      ((float4*)xcs)[i] = v;
    }
    if (tid < CL * 32)
      ((float4*)des)[tid] = ((const float4*)(delta + (size_t)(b * TT + t0) * DIN))[tid];
    if (tid < CL * 16)
      ((float4*)Bs)[tid] = ((const float4*)(Bb + (size_t)(b * TT + t0) * NS))[tid];
  }
  float cw0 = cw[d * 4 + 0], cw1 = cw[d * 4 + 1], cw2 = cw[d * 4 + 2], cw3 = cw[d * 4 + 3];
  float cbd = cb[d];
  int nb = g * 8;
  float a2r[8];
#pragma unroll
  for (int j = 0; j < 8; ++j) a2r[j] = a2g[nb + j];
  __syncthreads();
  float hf[8], hr[8], Pp[8];
#pragma unroll
  for (int j = 0; j < 8; ++j) { hf[j] = 0.f; hr[j] = 0.f; Pp[j] = 1.f; }
  float sd = 0.f;
  float w0 = xcs[0 * DIN + d], w1 = xcs[1 * DIN + d], w2 = xcs[2 * DIN + d];
#pragma unroll
  for (int i = 0; i < CL; ++i) {
    float w3 = xcs[(i + 3) * DIN + d];
    float xconv = fmaf(cw0, w0, fmaf(cw1, w1, fmaf(cw2, w2, fmaf(cw3, w3, cbd))));
    float de = des[i * DIN + d];
    sd += de;
    float dxv = de * xconv;
#pragma unroll
    for (int jq = 0; jq < 2; ++jq) {
      float4 bq = *(const float4*)&Bs[i * NS + nb + jq * 4];
      float b0 = dxv * bq.x, b1 = dxv * bq.y, b2 = dxv * bq.z, b3 = dxv * bq.w;
      float e0 = fexp2(de * a2r[jq * 4 + 0]);
      float e1 = fexp2(de * a2r[jq * 4 + 1]);
      float e2 = fexp2(de * a2r[jq * 4 + 2]);
      float e3 = fexp2(de * a2r[jq * 4 + 3]);
      hf[jq * 4 + 0] = fmaf(e0, hf[jq * 4 + 0], b0);
      hr[jq * 4 + 0] = fmaf(Pp[jq * 4 + 0], b0, hr[jq * 4 + 0]); Pp[jq * 4 + 0] *= e0;
      hf[jq * 4 + 1] = fmaf(e1, hf[jq * 4 + 1], b1);
      hr[jq * 4 + 1] = fmaf(Pp[jq * 4 + 1], b1, hr[jq * 4 + 1]); Pp[jq * 4 + 1] *= e1;
      hf[jq * 4 + 2] = fmaf(e2, hf[jq * 4 + 2], b2);
      hr[jq * 4 + 2] = fmaf(Pp[jq * 4 + 2], b2, hr[jq * 4 + 2]); Pp[jq * 4 + 2] *= e2;
      hf[jq * 4 + 3] = fmaf(e3, hf[jq * 4 + 3], b3);
      hr[jq * 4 + 3] = fmaf(Pp[jq * 4 + 3], b3, hr[jq * 4 + 3]); Pp[jq * 4 + 3] *= e3;
    }
    w0 = w1; w1 = w2; w2 = w3;
  }
  size_t h0 = (((size_t)(0 * NC + c) * BB + b) * NS + nb) * DIN + d;
  size_t h1 = (((size_t)(1 * NC + c) * BB + b) * NS + nb) * DIN + d;
#pragma unroll
  for (int j = 0; j < 8; ++j) {
    hend[h0 + (size_t)j * DIN] = hf[j];
    hend[h1 + (size_t)j * DIN] = hr[j];
  }
  if (g == 0) sumd[(c * BB + b) * DIN + d] = sd;
}

// ---- K3: within-super prefixes (8-chains, fully parallel) + delta prefixes ----
__global__ __launch_bounds__(512) void k_comb2A(
    const float* __restrict__ hend, float* __restrict__ hinL,
    const float* __restrict__ sumd, const float* __restrict__ a2g,
    float* __restrict__ S, float* __restrict__ sumdS,
    float* __restrict__ sumdPf, float* __restrict__ sumdPr) {
  int idx = blockIdx.x * 512 + threadIdx.x;   // 2*2*16*64*128 = 524288
  int dd = idx & 127;
  int n = (idx >> 7) & 63;
  int sp = (idx >> 13) & 15;
  int bd = idx >> 17;
  int b = bd >> 1, dir = bd & 1;
  float a2n = a2g[n];
  float carry = 0.f;
  float running = 0.f;
#pragma unroll
  for (int k = 0; k < SUPW; ++k) {
    int cc = sp * SUPW + (dir ? (SUPW - 1 - k) : k);
    float sdv = sumd[(cc * BB + b) * DIN + dd];
    if (n == 0) {
      if (dir) sumdPr[(cc * BB + b) * DIN + dd] = running;
      else     sumdPf[(cc * BB + b) * DIN + dd] = running;
      running += sdv;
      if (dir == 0 && k == SUPW - 1) sumdS[(sp * BB + b) * DIN + dd] = running;
    }
    float e = fexp2(a2n * sdv);
    size_t hb = (((size_t)(dir * NC + cc) * BB + b) * NS + n) * DIN + dd;
    float tmp = hend[hb];
    hinL[hb] = carry;
    carry = fmaf(e, carry, tmp);
  }
  S[((((size_t)dir * NSUP + sp) * BB + b) * NS + n) * DIN + dd] = carry;
}

// ---- K4: chain over 16 supers (loads hoisted) -> Csup ----
__global__ __launch_bounds__(256) void k_comb2B(
    const float* __restrict__ S, const float* __restrict__ sumdS,
    const float* __restrict__ a2g, float* __restrict__ Csup) {
  int idx = blockIdx.x * 256 + threadIdx.x;   // 2*2*64*128 = 32768
  int dd = idx & 127;
  int n = (idx >> 7) & 63;
  int bd = idx >> 13;
  int b = bd >> 1, dir = bd & 1;
  float a2n = a2g[n];
  float sdS[NSUP], Sv[NSUP];
#pragma unroll
  for (int sp = 0; sp < NSUP; ++sp) {
    sdS[sp] = sumdS[(sp * BB + b) * DIN + dd];
    Sv[sp] = S[((((size_t)dir * NSUP + sp) * BB + b) * NS + n) * DIN + dd];
  }
  float carry = 0.f;
#pragma unroll
  for (int k = 0; k < NSUP; ++k) {
    int sp = dir ? (NSUP - 1 - k) : k;
    Csup[((((size_t)dir * NSUP + sp) * BB + b) * NS + n) * DIN + dd] = carry;
    carry = fmaf(fexp2(a2n * sdS[sp]), carry, Sv[sp]);
  }
}

// ---- K5: full local scans with reconstructed init; y reduce + atomic out ----
__global__ __launch_bounds__(1024) void k_scan2(
    const float* __restrict__ xcin, const float* __restrict__ delta,
    const float* __restrict__ Bb, const float* __restrict__ Cb,
    const float* __restrict__ a2g, const float* __restrict__ cw,
    const float* __restrict__ cb, const float* __restrict__ Dp,
    const float* __restrict__ hinL, const float* __restrict__ Csup,
    const float* __restrict__ sumdPf, const float* __restrict__ sumdPr,
    float* __restrict__ out) {
  __shared__ float yred[8][4][DIN];   // 16 KB
  int c = blockIdx.x;
  int b = blockIdx.y >> 1, dir = blockIdx.y & 1;
  int tid = threadIdx.x;
  int d = tid & 127;
  int g = __builtin_amdgcn_readfirstlane(tid >> 7);  // 8 n-groups of 8
  float cw0 = cw[d * 4 + 0], cw1 = cw[d * 4 + 1], cw2 = cw[d * 4 + 2], cw3 = cw[d * 4 + 3];
  float cbd = cb[d];
  float Dd = Dp[d];
  int nb = g * 8;
  float a2r[8];
#pragma unroll
  for (int j = 0; j < 8; ++j) a2r[j] = a2g[nb + j];
  int sp = c >> 3;
  float Sloc = dir ? sumdPr[(c * BB + b) * DIN + d] : sumdPf[(c * BB + b) * DIN + d];
  float h[8];
  size_t hb0 = (((size_t)(dir * NC + c) * BB + b) * NS + nb) * DIN + d;
  size_t sb0 = ((((size_t)dir * NSUP + sp) * BB + b) * NS + nb) * DIN + d;
#pragma unroll
  for (int j = 0; j < 8; ++j) {
    float pe = fexp2(a2r[j] * Sloc);
    h[j] = fmaf(pe, Csup[sb0 + (size_t)j * DIN], hinL[hb0 + (size_t)j * DIN]);
  }
  int t0 = c * CL;
  const float* __restrict__ xcB = xcin + (size_t)b * TT * DIN + d;
  const float* __restrict__ deB = delta + (size_t)b * TT * DIN + d;
  const float* __restrict__ BbB = Bb + (size_t)b * TT * NS + nb;
  const float* __restrict__ CbB = Cb + (size_t)b * TT * NS + nb;
  bool addD = (g == 0) && (dir == 0);
  float w0, w1, w2, w3;
  if (dir == 0) {
    int t = t0;
    w0 = (t - 3 >= 0) ? xcB[(t - 3) * DIN] : 0.f;
    w1 = (t - 2 >= 0) ? xcB[(t - 2) * DIN] : 0.f;
    w2 = (t - 1 >= 0) ? xcB[(t - 1) * DIN] : 0.f;
    w3 = xcB[t * DIN];
#pragma unroll
    for (int i = 0; i < CL; ++i) {
      float xconv = fmaf(cw0, w0, fmaf(cw1, w1, fmaf(cw2, w2, fmaf(cw3, w3, cbd))));
      float de = deB[t * DIN];
      float dxv = de * xconv;
      float yv = addD ? Dd * xconv : 0.f;
#pragma unroll
      for (int jq = 0; jq < 2; ++jq) {
        float4 bq = *(const float4*)&BbB[t * NS + jq * 4];
        float4 cq = *(const float4*)&CbB[t * NS + jq * 4];
        float e0 = fexp2(de * a2r[jq * 4 + 0]);
        h[jq * 4 + 0] = fmaf(e0, h[jq * 4 + 0], dxv * bq.x); yv = fmaf(h[jq * 4 + 0], cq.x, yv);
        float e1 = fexp2(de * a2r[jq * 4 + 1]);
        h[jq * 4 + 1] = fmaf(e1, h[jq * 4 + 1], dxv * bq.y); yv = fmaf(h[jq * 4 + 1], cq.y, yv);
        float e2 = fexp2(de * a2r[jq * 4 + 2]);
        h[jq * 4 + 2] = fmaf(e2, h[jq * 4 + 2], dxv * bq.z); yv = fmaf(h[jq * 4 + 2], cq.z, yv);
        float e3 = fexp2(de * a2r[jq * 4 + 3]);
        h[jq * 4 + 3] = fmaf(e3, h[jq * 4 + 3], dxv * bq.w); yv = fmaf(h[jq * 4 + 3], cq.w, yv);
      }
      yred[g][i & 3][d] = yv;
      if ((i & 3) == 3) {
        __syncthreads();
        if (tid < 512) {
          int q = tid >> 7, d2 = tid & 127;
          float s = ((yred[0][q][d2] + yred[1][q][d2]) + (yred[2][q][d2] + yred[3][q][d2])) +
                    ((yred[4][q][d2] + yred[5][q][d2]) + (yred[6][q][d2] + yred[7][q][d2]));
          int tg = t0 + (i - 3 + q);
          unsafeAtomicAdd(&out[((size_t)b * TT + tg) * DIN + d2], s);
        }
        __syncthreads();
      }
      if (i < CL - 1) { ++t; w0 = w1; w1 = w2; w2 = w3; w3 = xcB[t * DIN]; }
    }
  } else {
    int t = t0 + CL - 1;
    w3 = xcB[t * DIN];
    w2 = xcB[(t - 1) * DIN];
    w1 = xcB[(t - 2) * DIN];
    w0 = xcB[(t - 3) * DIN];
#pragma unroll
    for (int i = 0; i < CL; ++i) {
      float xconv = fmaf(cw0, w0, fmaf(cw1, w1, fmaf(cw2, w2, fmaf(cw3, w3, cbd))));
      float de = deB[t * DIN];
      float dxv = de * xconv;
      float yv = 0.f;
#pragma unroll
      for (int jq = 0; jq < 2; ++jq) {
        float4 bq = *(const float4*)&BbB[t * NS + jq * 4];
        float4 cq = *(const float4*)&CbB[t * NS + jq * 4];
        float e0 = fexp2(de * a2r[jq * 4 + 0]);
        h[jq * 4 + 0] = fmaf(e0, h[jq * 4 + 0], dxv * bq.x); yv = fmaf(h[jq * 4 + 0], cq.x, yv);
        float e1 = fexp2(de * a2r[jq * 4 + 1]);
        h[jq * 4 + 1] = fmaf(e1, h[jq * 4 + 1], dxv * bq.y); yv = fmaf(h[jq * 4 + 1], cq.y, yv);
        float e2 = fexp2(de * a2r[jq * 4 + 2]);
        h[jq * 4 + 2] = fmaf(e2, h[jq * 4 + 2], dxv * bq.z); yv = fmaf(h[jq * 4 + 2], cq.z, yv);
        float e3 = fexp2(de * a2r[jq * 4 + 3]);
        h[jq * 4 + 3] = fmaf(e3, h[jq * 4 + 3], dxv * bq.w); yv = fmaf(h[jq * 4 + 3], cq.w, yv);
      }
      yred[g][i & 3][d] = yv;
      if ((i & 3) == 3) {
        __syncthreads();
        if (tid < 512) {
          int q = tid >> 7, d2 = tid & 127;
          float s = ((yred[0][q][d2] + yred[1][q][d2]) + (yred[2][q][d2] + yred[3][q][d2])) +
                    ((yred[4][q][d2] + yred[5][q][d2]) + (yred[6][q][d2] + yred[7][q][d2]));
          int tg = t0 + CL - 1 - (i - 3 + q);
          unsafeAtomicAdd(&out[((size_t)b * TT + tg) * DIN + d2], s);
        }
        __syncthreads();
      }
      if (i < CL - 1) { --t; w3 = w2; w2 = w1; w1 = w0; w0 = (t - 3 >= 0) ? xcB[(t - 3) * DIN] : 0.f; }
    }
  }
}

extern "C" void kernel_launch(void* const* d_in, const int* in_sizes, int n_in,
                              void* d_out, int out_size, void* d_ws, size_t ws_size,
                              hipStream_t stream) {
  const float* x  = (const float*)d_in[0];
  const float* W  = (const float*)d_in[1];
  const float* cw = (const float*)d_in[2];
  const float* cb = (const float*)d_in[3];
  const float* A  = (const float*)d_in[4];
  const float* Dp = (const float*)d_in[5];
  float* out = (float*)d_out;

  float* ws = (float*)d_ws;
  float* xcin   = ws;                      // 524288
  float* delta  = xcin + 524288;           // 524288
  float* Bbuf   = delta + 524288;          // 262144
  float* Cbuf   = Bbuf + 262144;           // 262144
  float* a2g    = Cbuf + 262144;           // 128
  float* sumd   = a2g + 128;               // 32768
  float* sumdPf = sumd + 32768;            // 32768
  float* sumdPr = sumdPf + 32768;          // 32768
  float* sumdS  = sumdPr + 32768;          // 4096
  float* hendb  = sumdS + 4096;            // 4194304
  float* hinL   = hendb + 4194304;         // 4194304
  float* Sb     = hinL + 4194304;          // 524288
  float* Csup   = Sb + 524288;             // 524288
  // total ~44.5 MB

  hipMemsetAsync(d_out, 0, (size_t)(BB * TT * DIN) * sizeof(float), stream);
  hipLaunchKernelGGL(k_proj,   dim3(32, 24), dim3(128), 0, stream,
                     x, W, A, xcin, delta, Bbuf, Cbuf, a2g);
  hipLaunchKernelGGL(k_scan1,  dim3(NC, BB), dim3(1024), 0, stream,
                     xcin, delta, Bbuf, a2g, cw, cb, hendb, sumd);
  hipLaunchKernelGGL(k_comb2A, dim3(1024), dim3(512), 0, stream,
                     hendb, hinL, sumd, a2g, Sb, sumdS, sumdPf, sumdPr);
  hipLaunchKernelGGL(k_comb2B, dim3(128), dim3(256), 0, stream,
                     Sb, sumdS, a2g, Csup);
  hipLaunchKernelGGL(k_scan2,  dim3(NC, BB * 2), dim3(1024), 0, stream,
                     xcin, delta, Bbuf, Cbuf, a2g, cw, cb, Dp, hinL, Csup,
                     sumdPf, sumdPr, out);
}

// Round 6
// 67.034 us; speedup vs baseline: 2.4093x; 1.1106x over previous
//
#include <hip/hip_runtime.h>

#define BB   2
#define TT   2048
#define DIN  128
#define NS   64
#define CL   16
#define NC   128     // TT/CL
#define NSUP 16
#define SUPW 8       // NC/NSUP
#define L2E  1.4426950408889634f

#if __has_builtin(__builtin_amdgcn_exp2f)
__device__ __forceinline__ float fexp2(float x) { return __builtin_amdgcn_exp2f(x); }
#else
__device__ __forceinline__ float fexp2(float x) { return exp2f(x); }
#endif

// ---- K1: xp = x @ W^T ; split into xcin / delta(sigmoid) / B / C ; a2 ----
__global__ __launch_bounds__(128) void k_proj(
    const float* __restrict__ x, const float* __restrict__ W,
    const float* __restrict__ A,
    float* __restrict__ xcin, float* __restrict__ delta,
    float* __restrict__ Bb, float* __restrict__ Cb, float* __restrict__ a2g) {
  __shared__ float xs[128 * 65];
  int tile = blockIdx.x, rg = blockIdx.y, tid = threadIdx.x;
  int base = tile * 128;
  const float4* __restrict__ x4 = (const float4*)(x + (size_t)base * 64);
  for (int i = tid; i < 128 * 16; i += 128) {
    float4 v = x4[i];
    int row = i >> 4, c4 = (i & 15) << 2;
    xs[row * 65 + c4 + 0] = v.x;
    xs[row * 65 + c4 + 1] = v.y;
    xs[row * 65 + c4 + 2] = v.z;
    xs[row * 65 + c4 + 3] = v.w;
  }
  if (tile == 0 && rg == 0 && tid < NS) {
    float s = 0.f;
    for (int m = 0; m < NS; ++m) s += A[tid * NS + m];
    a2g[tid] = s * L2E;
  }
  __syncthreads();
  float xr[64];
#pragma unroll
  for (int k = 0; k < 64; ++k) xr[k] = xs[tid * 65 + k];
  int bt = base + tid;
#pragma unroll 4
  for (int rr = 0; rr < 16; ++rr) {
    int r = rg * 16 + rr;
    const float* __restrict__ wrow = W + r * 64;
    float a0 = 0.f, a1 = 0.f, a2 = 0.f, a3 = 0.f;
#pragma unroll
    for (int k = 0; k < 64; k += 4) {
      a0 = fmaf(xr[k + 0], wrow[k + 0], a0);
      a1 = fmaf(xr[k + 1], wrow[k + 1], a1);
      a2 = fmaf(xr[k + 2], wrow[k + 2], a2);
      a3 = fmaf(xr[k + 3], wrow[k + 3], a3);
    }
    float acc = (a0 + a1) + (a2 + a3);
    if (r < 128) {
      xcin[(size_t)bt * DIN + r] = acc;
    } else if (r < 256) {
      delta[(size_t)bt * DIN + (r - 128)] = 1.f / (1.f + fexp2(-acc * L2E));
    } else if (r < 320) {
      Bb[(size_t)bt * NS + (r - 256)] = acc;
    } else {
      Cb[(size_t)bt * NS + (r - 320)] = acc;
    }
  }
}

// ---- K2: merged fwd+rev local chunk scans (shared exp), LDS-staged ----
__global__ __launch_bounds__(1024) void k_scan1(
    const float* __restrict__ xcin, const float* __restrict__ delta,
    const float* __restrict__ Bb, const float* __restrict__ a2g,
    const float* __restrict__ cw, const float* __restrict__ cb,
    float* __restrict__ hend, float* __restrict__ sumd) {
  __shared__ float xcs[(CL + 3) * DIN];  // 9.7 KB
  __shared__ float des[CL * DIN];        // 8 KB
  __shared__ float Bs[CL * NS];          // 4 KB
  int c = blockIdx.x, b = blockIdx.y;
  int tid = threadIdx.x;
  int d = tid & 127;
  int g = __builtin_amdgcn_readfirstlane(tid >> 7);  // 8 n-groups of 8
  int t0 = c * CL;
  {
    const float* __restrict__ xcB = xcin + (size_t)b * TT * DIN;
    for (int i = tid; i < (CL + 3) * 32; i += 1024) {
      int row = i >> 5, c4 = i & 31;
      int t = t0 - 3 + row;
      float4 v = make_float4(0.f, 0.f, 0.f, 0.f);
      if (t >= 0) v = ((const float4*)(xcB + (size_t)t * DIN))[c4];
      ((float4*)xcs)[i] = v;
    }
    if (tid < CL * 32)
      ((float4*)des)[tid] = ((const float4*)(delta + (size_t)(b * TT + t0) * DIN))[tid];
    if (tid < CL * 16)
      ((float4*)Bs)[tid] = ((const float4*)(Bb + (size_t)(b * TT + t0) * NS))[tid];
  }
  float cw0 = cw[d * 4 + 0], cw1 = cw[d * 4 + 1], cw2 = cw[d * 4 + 2], cw3 = cw[d * 4 + 3];
  float cbd = cb[d];
  int nb = g * 8;
  float a2r[8];
#pragma unroll
  for (int j = 0; j < 8; ++j) a2r[j] = a2g[nb + j];
  __syncthreads();
  float hf[8], hr[8], Pp[8];
#pragma unroll
  for (int j = 0; j < 8; ++j) { hf[j] = 0.f; hr[j] = 0.f; Pp[j] = 1.f; }
  float sd = 0.f;
  float w0 = xcs[0 * DIN + d], w1 = xcs[1 * DIN + d], w2 = xcs[2 * DIN + d];
#pragma unroll
  for (int i = 0; i < CL; ++i) {
    float w3 = xcs[(i + 3) * DIN + d];
    float xconv = fmaf(cw0, w0, fmaf(cw1, w1, fmaf(cw2, w2, fmaf(cw3, w3, cbd))));
    float de = des[i * DIN + d];
    sd += de;
    float dxv = de * xconv;
#pragma unroll
    for (int jq = 0; jq < 2; ++jq) {
      float4 bq = *(const float4*)&Bs[i * NS + nb + jq * 4];
      float b0 = dxv * bq.x, b1 = dxv * bq.y, b2 = dxv * bq.z, b3 = dxv * bq.w;
      float e0 = fexp2(de * a2r[jq * 4 + 0]);
      float e1 = fexp2(de * a2r[jq * 4 + 1]);
      float e2 = fexp2(de * a2r[jq * 4 + 2]);
      float e3 = fexp2(de * a2r[jq * 4 + 3]);
      hf[jq * 4 + 0] = fmaf(e0, hf[jq * 4 + 0], b0);
      hr[jq * 4 + 0] = fmaf(Pp[jq * 4 + 0], b0, hr[jq * 4 + 0]); Pp[jq * 4 + 0] *= e0;
      hf[jq * 4 + 1] = fmaf(e1, hf[jq * 4 + 1], b1);
      hr[jq * 4 + 1] = fmaf(Pp[jq * 4 + 1], b1, hr[jq * 4 + 1]); Pp[jq * 4 + 1] *= e1;
      hf[jq * 4 + 2] = fmaf(e2, hf[jq * 4 + 2], b2);
      hr[jq * 4 + 2] = fmaf(Pp[jq * 4 + 2], b2, hr[jq * 4 + 2]); Pp[jq * 4 + 2] *= e2;
      hf[jq * 4 + 3] = fmaf(e3, hf[jq * 4 + 3], b3);
      hr[jq * 4 + 3] = fmaf(Pp[jq * 4 + 3], b3, hr[jq * 4 + 3]); Pp[jq * 4 + 3] *= e3;
    }
    w0 = w1; w1 = w2; w2 = w3;
  }
  size_t h0 = (((size_t)(0 * NC + c) * BB + b) * NS + nb) * DIN + d;
  size_t h1 = (((size_t)(1 * NC + c) * BB + b) * NS + nb) * DIN + d;
#pragma unroll
  for (int j = 0; j < 8; ++j) {
    hend[h0 + (size_t)j * DIN] = hf[j];
    hend[h1 + (size_t)j * DIN] = hr[j];
  }
  if (g == 0) sumd[(c * BB + b) * DIN + d] = sd;
}

// ---- K3: within-super prefixes (8-chains, fully parallel) + delta prefixes ----
__global__ __launch_bounds__(512) void k_comb2A(
    const float* __restrict__ hend, float* __restrict__ hinL,
    const float* __restrict__ sumd, const float* __restrict__ a2g,
    float* __restrict__ S, float* __restrict__ sumdS,
    float* __restrict__ sumdPf, float* __restrict__ sumdPr) {
  int idx = blockIdx.x * 512 + threadIdx.x;   // 2*2*16*64*128 = 524288
  int dd = idx & 127;
  int n = (idx >> 7) & 63;
  int sp = (idx >> 13) & 15;
  int bd = idx >> 17;
  int b = bd >> 1, dir = bd & 1;
  float a2n = a2g[n];
  float carry = 0.f;
  float running = 0.f;
#pragma unroll
  for (int k = 0; k < SUPW; ++k) {
    int cc = sp * SUPW + (dir ? (SUPW - 1 - k) : k);
    float sdv = sumd[(cc * BB + b) * DIN + dd];
    if (n == 0) {
      if (dir) sumdPr[(cc * BB + b) * DIN + dd] = running;
      else     sumdPf[(cc * BB + b) * DIN + dd] = running;
      running += sdv;
      if (dir == 0 && k == SUPW - 1) sumdS[(sp * BB + b) * DIN + dd] = running;
    }
    float e = fexp2(a2n * sdv);
    size_t hb = (((size_t)(dir * NC + cc) * BB + b) * NS + n) * DIN + dd;
    float tmp = hend[hb];
    hinL[hb] = carry;
    carry = fmaf(e, carry, tmp);
  }
  S[((((size_t)dir * NSUP + sp) * BB + b) * NS + n) * DIN + dd] = carry;
}

// ---- K4: chain over 16 supers (loads hoisted) -> Csup ----
__global__ __launch_bounds__(256) void k_comb2B(
    const float* __restrict__ S, const float* __restrict__ sumdS,
    const float* __restrict__ a2g, float* __restrict__ Csup) {
  int idx = blockIdx.x * 256 + threadIdx.x;   // 2*2*64*128 = 32768
  int dd = idx & 127;
  int n = (idx >> 7) & 63;
  int bd = idx >> 13;
  int b = bd >> 1, dir = bd & 1;
  float a2n = a2g[n];
  float sdS[NSUP], Sv[NSUP];
#pragma unroll
  for (int sp = 0; sp < NSUP; ++sp) {
    sdS[sp] = sumdS[(sp * BB + b) * DIN + dd];
    Sv[sp] = S[((((size_t)dir * NSUP + sp) * BB + b) * NS + n) * DIN + dd];
  }
  float carry = 0.f;
#pragma unroll
  for (int k = 0; k < NSUP; ++k) {
    int sp = dir ? (NSUP - 1 - k) : k;
    Csup[((((size_t)dir * NSUP + sp) * BB + b) * NS + n) * DIN + dd] = carry;
    carry = fmaf(fexp2(a2n * sdS[sp]), carry, Sv[sp]);
  }
}

// ---- K5: both-direction full scans in one block; LDS reduce; plain store ----
__global__ __launch_bounds__(1024) void k_scan2(
    const float* __restrict__ xcin, const float* __restrict__ delta,
    const float* __restrict__ Bb, const float* __restrict__ Cb,
    const float* __restrict__ a2g, const float* __restrict__ cw,
    const float* __restrict__ cb, const float* __restrict__ Dp,
    const float* __restrict__ hinL, const float* __restrict__ Csup,
    const float* __restrict__ sumdPf, const float* __restrict__ sumdPr,
    float* __restrict__ out) {
  __shared__ float yred[8][CL][DIN];   // 64 KB
  int c = blockIdx.x, b = blockIdx.y;
  int tid = threadIdx.x;
  int d = tid & 127;
  int g = __builtin_amdgcn_readfirstlane(tid >> 7);  // 0..7
  int dir = g >> 2;                                  // groups 0-3 fwd, 4-7 rev
  int nb = (g & 3) * 16;
  float cw0 = cw[d * 4 + 0], cw1 = cw[d * 4 + 1], cw2 = cw[d * 4 + 2], cw3 = cw[d * 4 + 3];
  float cbd = cb[d];
  float Dd = Dp[d];
  float a2r[16];
#pragma unroll
  for (int j = 0; j < 16; ++j) a2r[j] = a2g[nb + j];
  int sp = c >> 3;
  float Sloc = dir ? sumdPr[(c * BB + b) * DIN + d] : sumdPf[(c * BB + b) * DIN + d];
  float h[16];
  size_t hb0 = (((size_t)(dir * NC + c) * BB + b) * NS + nb) * DIN + d;
  size_t sb0 = ((((size_t)dir * NSUP + sp) * BB + b) * NS + nb) * DIN + d;
#pragma unroll
  for (int j = 0; j < 16; ++j) {
    float pe = fexp2(a2r[j] * Sloc);
    h[j] = fmaf(pe, Csup[sb0 + (size_t)j * DIN], hinL[hb0 + (size_t)j * DIN]);
  }
  int t0 = c * CL;
  const float* __restrict__ xcB = xcin + (size_t)b * TT * DIN + d;
  const float* __restrict__ deB = delta + (size_t)b * TT * DIN + d;
  const float* __restrict__ BbB = Bb + (size_t)b * TT * NS + nb;
  const float* __restrict__ CbB = Cb + (size_t)b * TT * NS + nb;
  bool addD = (g == 0);
  float w0, w1, w2, w3;
  if (dir == 0) {
    int t = t0;
    w0 = (t - 3 >= 0) ? xcB[(t - 3) * DIN] : 0.f;
    w1 = (t - 2 >= 0) ? xcB[(t - 2) * DIN] : 0.f;
    w2 = (t - 1 >= 0) ? xcB[(t - 1) * DIN] : 0.f;
    w3 = xcB[t * DIN];
#pragma unroll
    for (int i = 0; i < CL; ++i) {
      float xconv = fmaf(cw0, w0, fmaf(cw1, w1, fmaf(cw2, w2, fmaf(cw3, w3, cbd))));
      float de = deB[t * DIN];
      float dxv = de * xconv;
      float yv = addD ? Dd * xconv : 0.f;
#pragma unroll
      for (int jq = 0; jq < 4; ++jq) {
        float4 bq = *(const float4*)&BbB[t * NS + jq * 4];
        float4 cq = *(const float4*)&CbB[t * NS + jq * 4];
        float e0 = fexp2(de * a2r[jq * 4 + 0]);
        h[jq * 4 + 0] = fmaf(e0, h[jq * 4 + 0], dxv * bq.x); yv = fmaf(h[jq * 4 + 0], cq.x, yv);
        float e1 = fexp2(de * a2r[jq * 4 + 1]);
        h[jq * 4 + 1] = fmaf(e1, h[jq * 4 + 1], dxv * bq.y); yv = fmaf(h[jq * 4 + 1], cq.y, yv);
        float e2 = fexp2(de * a2r[jq * 4 + 2]);
        h[jq * 4 + 2] = fmaf(e2, h[jq * 4 + 2], dxv * bq.z); yv = fmaf(h[jq * 4 + 2], cq.z, yv);
        float e3 = fexp2(de * a2r[jq * 4 + 3]);
        h[jq * 4 + 3] = fmaf(e3, h[jq * 4 + 3], dxv * bq.w); yv = fmaf(h[jq * 4 + 3], cq.w, yv);
      }
      yred[g][i][d] = yv;
      if (i < CL - 1) { ++t; w0 = w1; w1 = w2; w2 = w3; w3 = xcB[t * DIN]; }
    }
  } else {
    int t = t0 + CL - 1;
    w3 = xcB[t * DIN];
    w2 = xcB[(t - 1) * DIN];
    w1 = xcB[(t - 2) * DIN];
    w0 = xcB[(t - 3) * DIN];
#pragma unroll
    for (int i = 0; i < CL; ++i) {
      float xconv = fmaf(cw0, w0, fmaf(cw1, w1, fmaf(cw2, w2, fmaf(cw3, w3, cbd))));
      float de = deB[t * DIN];
      float dxv = de * xconv;
      float yv = 0.f;
#pragma unroll
      for (int jq = 0; jq < 4; ++jq) {
        float4 bq = *(const float4*)&BbB[t * NS + jq * 4];
        float4 cq = *(const float4*)&CbB[t * NS + jq * 4];
        float e0 = fexp2(de * a2r[jq * 4 + 0]);
        h[jq * 4 + 0] = fmaf(e0, h[jq * 4 + 0], dxv * bq.x); yv = fmaf(h[jq * 4 + 0], cq.x, yv);
        float e1 = fexp2(de * a2r[jq * 4 + 1]);
        h[jq * 4 + 1] = fmaf(e1, h[jq * 4 + 1], dxv * bq.y); yv = fmaf(h[jq * 4 + 1], cq.y, yv);
        float e2 = fexp2(de * a2r[jq * 4 + 2]);
        h[jq * 4 + 2] = fmaf(e2, h[jq * 4 + 2], dxv * bq.z); yv = fmaf(h[jq * 4 + 2], cq.z, yv);
        float e3 = fexp2(de * a2r[jq * 4 + 3]);
        h[jq * 4 + 3] = fmaf(e3, h[jq * 4 + 3], dxv * bq.w); yv = fmaf(h[jq * 4 + 3], cq.w, yv);
      }
      yred[g][i][d] = yv;
      if (i < CL - 1) { --t; w3 = w2; w2 = w1; w1 = w0; w0 = (t - 3 >= 0) ? xcB[(t - 3) * DIN] : 0.f; }
    }
  }
  __syncthreads();
#pragma unroll
  for (int k = 0; k < 2; ++k) {
    int p = k * 1024 + tid;
    int i = p >> 7, d2 = p & 127;
    int ir = CL - 1 - i;
    float sf = (yred[0][i][d2] + yred[1][i][d2]) + (yred[2][i][d2] + yred[3][i][d2]);
    float sr = (yred[4][ir][d2] + yred[5][ir][d2]) + (yred[6][ir][d2] + yred[7][ir][d2]);
    out[((size_t)b * TT + t0 + i) * DIN + d2] = sf + sr;
  }
}

extern "C" void kernel_launch(void* const* d_in, const int* in_sizes, int n_in,
                              void* d_out, int out_size, void* d_ws, size_t ws_size,
                              hipStream_t stream) {
  const float* x  = (const float*)d_in[0];
  const float* W  = (const float*)d_in[1];
  const float* cw = (const float*)d_in[2];
  const float* cb = (const float*)d_in[3];
  const float* A  = (const float*)d_in[4];
  const float* Dp = (const float*)d_in[5];
  float* out = (float*)d_out;

  float* ws = (float*)d_ws;
  float* xcin   = ws;                      // 524288
  float* delta  = xcin + 524288;           // 524288
  float* Bbuf   = delta + 524288;          // 262144
  float* Cbuf   = Bbuf + 262144;           // 262144
  float* a2g    = Cbuf + 262144;           // 128
  float* sumd   = a2g + 128;               // 32768
  float* sumdPf = sumd + 32768;            // 32768
  float* sumdPr = sumdPf + 32768;          // 32768
  float* sumdS  = sumdPr + 32768;          // 4096
  float* hendb  = sumdS + 4096;            // 4194304
  float* hinL   = hendb + 4194304;         // 4194304
  float* Sb     = hinL + 4194304;          // 524288
  float* Csup   = Sb + 524288;             // 524288
  // total ~44.5 MB

  hipLaunchKernelGGL(k_proj,   dim3(32, 24), dim3(128), 0, stream,
                     x, W, A, xcin, delta, Bbuf, Cbuf, a2g);
  hipLaunchKernelGGL(k_scan1,  dim3(NC, BB), dim3(1024), 0, stream,
                     xcin, delta, Bbuf, a2g, cw, cb, hendb, sumd);
  hipLaunchKernelGGL(k_comb2A, dim3(1024), dim3(512), 0, stream,
                     hendb, hinL, sumd, a2g, Sb, sumdS, sumdPf, sumdPr);
  hipLaunchKernelGGL(k_comb2B, dim3(128), dim3(256), 0, stream,
                     Sb, sumdS, a2g, Csup);
  hipLaunchKernelGGL(k_scan2,  dim3(NC, BB), dim3(1024), 0, stream,
                     xcin, delta, Bbuf, Cbuf, a2g, cw, cb, Dp, hinL, Csup,
                     sumdPf, sumdPr, out);
}